// Round 2
// baseline (10066.322 us; speedup 1.0000x reference)
//
#include <hip/hip_runtime.h>

#define Bb 256
#define Tt 512
#define NF 64
#define H1u 256
#define H2u 128
#define G 8            // batch groups
#define BPG 32         // blocks per group
#define Bs 32          // batch per group
#define NBLK 256
#define NTHR 512
#define K1 320
#define K2 384

// ws offsets (floats)
#define OFF_WB1 0                               // [j 32][g 4][k 320][u 8]
#define SZ_WB1  (32*4*320*8)
#define OFF_WB2 (OFF_WB1+SZ_WB1)                // [j 32][g 4][k 384][u 4]
#define SZ_WB2  (32*4*384*4)
#define OFF_BB1 (OFF_WB2+SZ_WB2)                // [j 32][g 4][u 8]
#define SZ_BB1  (32*4*8)
#define OFF_BB2 (OFF_BB1+SZ_BB1)                // [j 32][g 4][u 4]
#define SZ_BB2  (32*4*4)
#define OFF_H1G (OFF_BB2+SZ_BB2)                // [G][2][256*32]
#define SZ_H1G  (G*2*H1u*Bs)
#define OFF_H2G (OFF_H1G+SZ_H1G)                // [G][2][128*32]
#define SZ_H2G  (G*2*H2u*Bs)
#define OFF_CTR (OFF_H2G+SZ_H2G)                // G counters spaced 32 u32
#define SZ_CTR  (G*32)
#define WS_MIN  (OFF_CTR+SZ_CTR)

__device__ __forceinline__ float sigf(float x) {
    return 1.0f / (1.0f + __expf(-x));
}
__device__ __forceinline__ float tanhfast(float x) {
    return 2.0f / (1.0f + __expf(-2.0f * x)) - 1.0f;
}

// Build per-block weight tiles + fused biases.
__global__ __launch_bounds__(256) void prep2(
    const float* __restrict__ Wih1, const float* __restrict__ Whh1,
    const float* __restrict__ bih1, const float* __restrict__ bhh1,
    const float* __restrict__ Wih2, const float* __restrict__ Whh2,
    const float* __restrict__ bih2, const float* __restrict__ bhh2,
    float* __restrict__ ws)
{
    const int stride = gridDim.x * blockDim.x;
    const int i0 = blockIdx.x * blockDim.x + threadIdx.x;
    // WB1: idx -> j,g,k,u ; row = g*256 + j*8 + u ; k<64 -> Wih1 else Whh1
    for (int idx = i0; idx < SZ_WB1; idx += stride) {
        int u = idx & 7;
        int k = (idx >> 3) % 320;
        int rem = idx / (320 * 8);
        int g = rem & 3;
        int j = rem >> 2;
        int row = g * H1u + j * 8 + u;
        ws[OFF_WB1 + idx] = (k < NF) ? Wih1[row * NF + k]
                                     : Whh1[row * H1u + (k - NF)];
    }
    // WB2: idx -> j,g,k,u ; row = g*128 + j*4 + u ; k<256 -> Wih2 else Whh2
    for (int idx = i0; idx < SZ_WB2; idx += stride) {
        int u = idx & 3;
        int k = (idx >> 2) % 384;
        int rem = idx / (384 * 4);
        int g = rem & 3;
        int j = rem >> 2;
        int row = g * H2u + j * 4 + u;
        ws[OFF_WB2 + idx] = (k < H1u) ? Wih2[row * H1u + k]
                                      : Whh2[row * H2u + (k - H1u)];
    }
    for (int idx = i0; idx < SZ_BB1; idx += stride) {
        int u = idx & 7;
        int g = (idx >> 3) & 3;
        int j = idx >> 5;
        int row = g * H1u + j * 8 + u;
        ws[OFF_BB1 + idx] = bih1[row] + bhh1[row];
    }
    for (int idx = i0; idx < SZ_BB2; idx += stride) {
        int u = idx & 3;
        int g = (idx >> 2) & 3;
        int j = idx >> 4;
        int row = g * H2u + j * 4 + u;
        ws[OFF_BB2 + idx] = bih2[row] + bhh2[row];
    }
}

__global__ __launch_bounds__(NTHR) void lstm_persist(
    const float* __restrict__ x, const float* __restrict__ wsf,
    float* __restrict__ h1g, float* __restrict__ h2g,
    unsigned* __restrict__ ctrs, float* __restrict__ out)
{
    // LDS: 57344 + 40960 + 24576 + 4096 + 2048 + 4096 + 2048 + 1024 + 512 + 128 + 64
    //    = 136,896 B  -> exactly 1 block/CU, grid 256 = all resident.
    __shared__ float xh1[448][32];      // rows: 0..63 x_t | 64..319 h1 | 320..447 h2
    __shared__ float W1s[4][320][8];
    __shared__ float W2s[4][384][4];
    __shared__ float scr1[4 * 8 * 32];
    __shared__ float scr2[4 * 4 * 32];
    __shared__ float act1[4][8][32];
    __shared__ float act2[4][4][32];
    __shared__ float c1s[8][32];
    __shared__ float c2s[4][32];
    __shared__ float bias1[4][8];
    __shared__ float bias2[4][4];

    const int tid  = threadIdx.x;
    const int g    = blockIdx.x & 7;     // group (likely = XCD)
    const int j    = blockIdx.x >> 3;    // row-slice within group (0..31)
    const int b0   = g * Bs;
    const int w    = tid >> 6;
    const int lane = tid & 63;
    const int gi   = w & 3;              // gate (i,f,g,o)
    const int uq   = w >> 2;             // unit quad (L1) / unit pair (L2)
    const int b    = lane & 31;          // batch within group
    const int kh   = lane >> 5;          // k-half

    // ---- one-time: weights -> LDS, zero cell state ----
    {
        const float* w1 = wsf + OFF_WB1 + (size_t)j * (4 * 320 * 8);
        float* d1 = &W1s[0][0][0];
        for (int i = tid * 4; i < 4 * 320 * 8; i += NTHR * 4)
            *(float4*)(d1 + i) = *(const float4*)(w1 + i);
        const float* w2 = wsf + OFF_WB2 + (size_t)j * (4 * 384 * 4);
        float* d2 = &W2s[0][0][0];
        for (int i = tid * 4; i < 4 * 384 * 4; i += NTHR * 4)
            *(float4*)(d2 + i) = *(const float4*)(w2 + i);
        if (tid < 32)  bias1[tid >> 3][tid & 7] = wsf[OFF_BB1 + j * 32 + tid];
        if (tid < 16)  bias2[tid >> 2][tid & 3] = wsf[OFF_BB2 + j * 16 + tid];
        if (tid < 256) c1s[tid >> 5][tid & 31] = 0.f;
        if (tid < 128) c2s[tid >> 5][tid & 31] = 0.f;
    }
    __syncthreads();

    unsigned* ctr = ctrs + g * 32;

    for (int t = 0; t <= Tt; ++t) {
        // ---- stage operand panel into LDS ----
        if (t < Tt) {
            const int sb = tid >> 4, kq = tid & 15;
            float4 xv = *(const float4*)(x + ((size_t)(b0 + sb) * Tt + t) * NF + kq * 4);
            xh1[kq * 4 + 0][sb] = xv.x;
            xh1[kq * 4 + 1][sb] = xv.y;
            xh1[kq * 4 + 2][sb] = xv.z;
            xh1[kq * 4 + 3][sb] = xv.w;
        }
        {
            const float* s1 = h1g + ((size_t)g * 2 + ((t + 1) & 1)) * (H1u * Bs);
            float* d = &xh1[64][0];
            for (int i = tid * 4; i < H1u * Bs; i += NTHR * 4)
                *(float4*)(d + i) = *(const float4*)(s1 + i);
            const float* s2 = h2g + ((size_t)g * 2 + (t & 1)) * (H2u * Bs);
            float* d2 = &xh1[320][0];
            for (int i = tid * 4; i < H2u * Bs; i += NTHR * 4)
                *(float4*)(d2 + i) = *(const float4*)(s2 + i);
        }
        __syncthreads();

        // ---- L1 accumulate: gate gi, units uq*4..+3, batch b, k-half kh ----
        float a0, a1, a2, a3;
        if (t < Tt) {
            if (kh == 0) {
                a0 = bias1[gi][uq * 4 + 0]; a1 = bias1[gi][uq * 4 + 1];
                a2 = bias1[gi][uq * 4 + 2]; a3 = bias1[gi][uq * 4 + 3];
            } else { a0 = a1 = a2 = a3 = 0.f; }
            const int kbase = kh * 160;
            #pragma unroll 4
            for (int k = 0; k < 160; ++k) {
                const int kk = kbase + k;
                const float hv = xh1[kk][b];
                const float4 wv = *(const float4*)&W1s[gi][kk][uq * 4];
                a0 = fmaf(wv.x, hv, a0);
                a1 = fmaf(wv.y, hv, a1);
                a2 = fmaf(wv.z, hv, a2);
                a3 = fmaf(wv.w, hv, a3);
            }
        }
        // ---- L2 accumulate (step t-1): gate gi, units uq*2..+1 ----
        float e0, e1;
        if (t >= 1) {
            if (kh == 0) {
                e0 = bias2[gi][uq * 2 + 0]; e1 = bias2[gi][uq * 2 + 1];
            } else { e0 = e1 = 0.f; }
            const int kbase = kh * 192;
            #pragma unroll 4
            for (int k = 0; k < 192; ++k) {
                const int kk = kbase + k;
                const float hv = xh1[64 + kk][b];
                const float2 wv = *(const float2*)&W2s[gi][kk][uq * 2];
                e0 = fmaf(wv.x, hv, e0);
                e1 = fmaf(wv.y, hv, e1);
            }
        }
        // ---- k-half reduction via LDS ----
        if (t < Tt && kh == 1) {
            scr1[(gi * 8 + uq * 4 + 0) * 32 + b] = a0;
            scr1[(gi * 8 + uq * 4 + 1) * 32 + b] = a1;
            scr1[(gi * 8 + uq * 4 + 2) * 32 + b] = a2;
            scr1[(gi * 8 + uq * 4 + 3) * 32 + b] = a3;
        }
        if (t >= 1 && kh == 1) {
            scr2[(gi * 4 + uq * 2 + 0) * 32 + b] = e0;
            scr2[(gi * 4 + uq * 2 + 1) * 32 + b] = e1;
        }
        __syncthreads();
        if (t < Tt && kh == 0) {
            a0 += scr1[(gi * 8 + uq * 4 + 0) * 32 + b];
            a1 += scr1[(gi * 8 + uq * 4 + 1) * 32 + b];
            a2 += scr1[(gi * 8 + uq * 4 + 2) * 32 + b];
            a3 += scr1[(gi * 8 + uq * 4 + 3) * 32 + b];
            if (gi == 2) {
                a0 = tanhfast(a0); a1 = tanhfast(a1);
                a2 = tanhfast(a2); a3 = tanhfast(a3);
            } else {
                a0 = sigf(a0); a1 = sigf(a1); a2 = sigf(a2); a3 = sigf(a3);
            }
            act1[gi][uq * 4 + 0][b] = a0;
            act1[gi][uq * 4 + 1][b] = a1;
            act1[gi][uq * 4 + 2][b] = a2;
            act1[gi][uq * 4 + 3][b] = a3;
        }
        if (t >= 1 && kh == 0) {
            e0 += scr2[(gi * 4 + uq * 2 + 0) * 32 + b];
            e1 += scr2[(gi * 4 + uq * 2 + 1) * 32 + b];
            if (gi == 2) { e0 = tanhfast(e0); e1 = tanhfast(e1); }
            else         { e0 = sigf(e0);     e1 = sigf(e1); }
            act2[gi][uq * 2 + 0][b] = e0;
            act2[gi][uq * 2 + 1][b] = e1;
        }
        __syncthreads();
        // ---- gating + state update + h writeback ----
        if (t < Tt && tid < 256) {
            const int u = tid >> 5, bb = tid & 31;
            const float iv = act1[0][u][bb], fv = act1[1][u][bb];
            const float gv = act1[2][u][bb], ov = act1[3][u][bb];
            float c = fmaf(fv, c1s[u][bb], iv * gv);
            c1s[u][bb] = c;
            const float h = ov * tanhfast(c);
            h1g[((size_t)g * 2 + (t & 1)) * (H1u * Bs) + (j * 8 + u) * 32 + bb] = h;
        }
        if (t >= 1 && tid >= 256 && tid < 384) {
            const int u = (tid >> 5) & 3, bb = tid & 31;
            const float iv = act2[0][u][bb], fv = act2[1][u][bb];
            const float gv = act2[2][u][bb], ov = act2[3][u][bb];
            float c = fmaf(fv, c2s[u][bb], iv * gv);
            c2s[u][bb] = c;
            const float h = ov * tanhfast(c);
            h2g[((size_t)g * 2 + ((t + 1) & 1)) * (H2u * Bs) + (j * 4 + u) * 32 + bb] = h;
            scr2[u * 32 + bb] = h;   // partials already consumed; reuse as h2 row
        }
        __syncthreads();
        if (t >= 1 && tid < 32) {
            const int s = t - 1;
            float4 hv = make_float4(scr2[tid], scr2[32 + tid],
                                    scr2[64 + tid], scr2[96 + tid]);
            *(float4*)(out + ((size_t)(b0 + tid) * Tt + s) * H2u + j * 4) = hv;
            if (s == Tt - 1)
                *(float4*)(out + (size_t)Bb * Tt * H2u + (size_t)(b0 + tid) * H2u + j * 4) = hv;
        }
        // ---- group barrier (monotonic counter, release/acquire, agent scope) ----
        if (tid == 0) {
            __hip_atomic_fetch_add(ctr, 1u, __ATOMIC_RELEASE, __HIP_MEMORY_SCOPE_AGENT);
            const unsigned tgt = (unsigned)(BPG * (t + 1));
            while (__hip_atomic_load(ctr, __ATOMIC_ACQUIRE, __HIP_MEMORY_SCOPE_AGENT) < tgt)
                __builtin_amdgcn_s_sleep(1);
        }
        __syncthreads();
    }
}

extern "C" void kernel_launch(void* const* d_in, const int* in_sizes, int n_in,
                              void* d_out, int out_size, void* d_ws, size_t ws_size,
                              hipStream_t stream) {
    const float* x    = (const float*)d_in[0];
    const float* Wih1 = (const float*)d_in[1];
    const float* Whh1 = (const float*)d_in[2];
    const float* bih1 = (const float*)d_in[3];
    const float* bhh1 = (const float*)d_in[4];
    const float* Wih2 = (const float*)d_in[5];
    const float* Whh2 = (const float*)d_in[6];
    const float* bih2 = (const float*)d_in[7];
    const float* bhh2 = (const float*)d_in[8];
    float* ws  = (float*)d_ws;
    float* out = (float*)d_out;

    prep2<<<256, 256, 0, stream>>>(Wih1, Whh1, bih1, bhh1,
                                   Wih2, Whh2, bih2, bhh2, ws);
    // zero h-state parity buffers + barrier counters (must be re-zeroed every
    // launch: counters are monotonically consumed within one run)
    hipMemsetAsync((void*)(ws + OFF_H1G), 0,
                   (size_t)(SZ_H1G + SZ_H2G + SZ_CTR) * sizeof(float), stream);
    lstm_persist<<<NBLK, NTHR, 0, stream>>>(
        x, ws, ws + OFF_H1G, ws + OFF_H2G,
        (unsigned*)(ws + OFF_CTR), out);
}

// Round 3
// 6563.245 us; speedup vs baseline: 1.5337x; 1.5337x over previous
//
#include <hip/hip_runtime.h>

typedef unsigned long long ull;

#define Bb 256
#define Tt 512
#define NF 64
#define H1u 256
#define H2u 128
#define Bs 32
#define K1 320
#define K2 384
#define NTHR 512
#define NBLK 256

// ws offsets (floats)
#define OFF_W1P 0
#define SZ_W1P  (32*K1*32)                 // 327680  [j][k][r32], r = u*4+gate
#define OFF_W2P (OFF_W1P+SZ_W1P)           // [j][k][r16]
#define SZ_W2P  (32*K2*16)                 // 196608
#define OFF_B1P (OFF_W2P+SZ_W2P)
#define SZ_B1P  (32*32)
#define OFF_B2P (OFF_B1P+SZ_B1P)
#define SZ_B2P  (32*16)
#define OFF_H1G (OFF_B2P+SZ_B2P)           // [par2][grp8][U256][b32]
#define SZ_H1G  (2*8*H1u*Bs)
#define OFF_H2G (OFF_H1G+SZ_H1G)           // [par2][grp8][U128][b32]
#define SZ_H2G  (2*8*H2u*Bs)
#define OFF_CTR (OFF_H2G+SZ_H2G)           // 8 counters spaced 32 u32
#define SZ_CTR  (8*32)

__device__ __forceinline__ float sigf(float x) {
    return 1.0f / (1.0f + __expf(-x));
}
__device__ __forceinline__ float tanhfast(float x) {
    return 2.0f / (1.0f + __expf(-2.0f * x)) - 1.0f;
}
__device__ __forceinline__ ull pack2(float a, float b) {
    return (ull)__float_as_uint(a) | ((ull)__float_as_uint(b) << 32);
}
__device__ __forceinline__ float gate_h(float i_, float f_, float g_, float o_, float& c) {
    float iv = sigf(i_), fv = sigf(f_), gv = tanhfast(g_), ov = sigf(o_);
    c = fmaf(fv, c, iv * gv);
    return ov * tanhfast(c);
}

// ---------------- prep: weight relayout ----------------
__global__ __launch_bounds__(256) void prep3(
    const float* __restrict__ Wih1, const float* __restrict__ Whh1,
    const float* __restrict__ bih1, const float* __restrict__ bhh1,
    const float* __restrict__ Wih2, const float* __restrict__ Whh2,
    const float* __restrict__ bih2, const float* __restrict__ bhh2,
    float* __restrict__ ws)
{
    const int stride = gridDim.x * blockDim.x;
    const int i0 = blockIdx.x * blockDim.x + threadIdx.x;
    for (int idx = i0; idx < SZ_W1P; idx += stride) {
        int r = idx & 31, k = (idx >> 5) % K1, jb = idx / (K1 * 32);
        int gate = r & 3, u = r >> 2;
        int grow = gate * H1u + jb * 8 + u;
        ws[OFF_W1P + idx] = (k < NF) ? Wih1[grow * NF + k]
                                     : Whh1[grow * H1u + (k - NF)];
    }
    for (int idx = i0; idx < SZ_W2P; idx += stride) {
        int r = idx & 15, k = (idx >> 4) % K2, jb = idx / (K2 * 16);
        int gate = r & 3, u = r >> 2;
        int grow = gate * H2u + jb * 4 + u;
        ws[OFF_W2P + idx] = (k < H1u) ? Wih2[grow * H1u + k]
                                      : Whh2[grow * H2u + (k - H1u)];
    }
    for (int idx = i0; idx < SZ_B1P; idx += stride) {
        int jb = idx >> 5, r = idx & 31;
        int grow = (r & 3) * H1u + jb * 8 + (r >> 2);
        ws[OFF_B1P + idx] = bih1[grow] + bhh1[grow];
    }
    for (int idx = i0; idx < SZ_B2P; idx += stride) {
        int jb = idx >> 4, r = idx & 15;
        int grow = (r & 3) * H2u + jb * 4 + (r >> 2);
        ws[OFF_B2P + idx] = bih2[grow] + bhh2[grow];
    }
}

// ---------------- staging helpers ----------------
__device__ __forceinline__ void stage_x(const float* __restrict__ x, float* dyn,
                                        int b0, int t, int tid)
{
    const int fq = tid >> 5, b = tid & 31;
    const float4 xv = *(const float4*)&x[(((size_t)(b0 + b)) * Tt + t) * NF + fq * 4];
    dyn[(fq * 4 + 0) * 32 + b] = xv.x;
    dyn[(fq * 4 + 1) * 32 + b] = xv.y;
    dyn[(fq * 4 + 2) * 32 + b] = xv.z;
    dyn[(fq * 4 + 3) * 32 + b] = xv.w;
}

__device__ __forceinline__ void stage_h(const ull* h1q, const ull* h2q, float* dyn,
                                        int par1, int par2, int grp, int tid)
{
    const int up = tid >> 4, bp = tid & 15;
    const size_t base1 = ((size_t)(par1 * 8 + grp)) * (H1u * 16);
    #pragma unroll
    for (int i = 0; i < 8; ++i) {
        const int U = up * 8 + i;
        ull v = __hip_atomic_load(&h1q[base1 + U * 16 + bp],
                                  __ATOMIC_RELAXED, __HIP_MEMORY_SCOPE_AGENT);
        *(ull*)&dyn[(64 + U) * 32 + bp * 2] = v;
    }
    const size_t base2 = ((size_t)(par2 * 8 + grp)) * (H2u * 16);
    #pragma unroll
    for (int i = 0; i < 4; ++i) {
        const int U2 = up * 4 + i;
        ull v = __hip_atomic_load(&h2q[base2 + U2 * 16 + bp],
                                  __ATOMIC_RELAXED, __HIP_MEMORY_SCOPE_AGENT);
        *(ull*)&dyn[(320 + U2) * 32 + bp * 2] = v;
    }
}

// ---------------- persistent recurrence ----------------
__global__ __launch_bounds__(NTHR, 1) void lstm_v3(
    const float* __restrict__ x, const float* __restrict__ wsf,
    float* h1g, float* h2g, unsigned* ctrs, float* __restrict__ out)
{
    __shared__ __align__(16) float W1s[K1 * 32];    // 40 KB  [k][r]
    __shared__ __align__(16) float W2s[K2 * 16];    // 24 KB  [k][r]
    __shared__ __align__(16) float dyn[14880];      // 59.5 KB panel [448][32] / scr overlay
    __shared__ __align__(16) float h2tile[4 * 36];

    const int tid = threadIdx.x;
    const int grp = blockIdx.x & 7;
    const int j   = blockIdx.x >> 3;
    const int b0  = grp * Bs;

    // one-time: weights -> LDS
    {
        const float* w1 = wsf + OFF_W1P + (size_t)j * (K1 * 32);
        #pragma unroll
        for (int i = tid * 4; i < K1 * 32; i += NTHR * 4)
            *(float4*)&W1s[i] = *(const float4*)&w1[i];
        const float* w2 = wsf + OFF_W2P + (size_t)j * (K2 * 16);
        #pragma unroll
        for (int i = tid * 4; i < K2 * 16; i += NTHR * 4)
            *(float4*)&W2s[i] = *(const float4*)&w2[i];
    }

    // thread decompositions
    const int kseg  = tid >> 6;             // 0..7   (L1: 40 k each)
    const int rq    = (tid >> 3) & 7;       // unit within block (L1)
    const int bq    = tid & 7;              // batch quad
    const int kseg2 = tid >> 5;             // 0..15  (L2: 24 k each)
    const int rq2   = (tid >> 3) & 3;       // unit within block (L2)
    const int bq2   = tid & 7;
    const int kb1   = kseg * 40;
    const int kb2   = kseg2 * 24;
    const int pos   = tid & 63;             // L1 scratch position
    const int pos2  = (rq2 << 3) | bq2;     // L2 scratch position (0..31)
    const int sw1   = pos & 3;
    const int sw2   = pos2 & 3;

    float4 c1r = {0.f, 0.f, 0.f, 0.f}, c2r = {0.f, 0.f, 0.f, 0.f};
    float4 b1v = {0.f, 0.f, 0.f, 0.f}, b2v = {0.f, 0.f, 0.f, 0.f};
    if (kseg == 0)   b1v = *(const float4*)&wsf[OFF_B1P + j * 32 + rq * 4];
    if (kseg2 == 15) b2v = *(const float4*)&wsf[OFF_B2P + j * 16 + rq2 * 4];

    const ull* h1q = (const ull*)h1g;
    const ull* h2q = (const ull*)h2g;
    ull* h1qw = (ull*)h1g;
    ull* h2qw = (ull*)h2g;
    unsigned* ctr = ctrs + grp * 32;

    // prologue: panel for step 0 (h buffers are zeroed)
    stage_x(x, dyn, b0, 0, tid);
    stage_h(h1q, h2q, dyn, 1, 0, grp, tid);
    __syncthreads();

    const float4* hp4 = (const float4*)dyn;   // hp4[k*8 + bq]
    const float4* w14 = (const float4*)W1s;   // w14[k*8 + rq]
    const float4* w24 = (const float4*)W2s;   // w24[k*4 + rq2]

    for (int t = 0; t <= Tt; ++t) {
        const bool L1a = (t < Tt);
        const bool L2a = (t >= 1);

        float4 A0 = {0,0,0,0}, A1 = A0, A2 = A0, A3 = A0;
        float4 E0 = A0, E1 = A0, E2 = A0, E3 = A0;

        // ---- A: register-tiled GEMM slices ----
        if (L1a) {
            const float4* ph = hp4 + (size_t)kb1 * 8 + bq;
            const float4* pw = w14 + (size_t)kb1 * 8 + rq;
            #pragma unroll 8
            for (int k = 0; k < 40; ++k) {
                const float4 hv = ph[k * 8];
                const float4 wv = pw[k * 8];
                A0.x = fmaf(wv.x, hv.x, A0.x); A0.y = fmaf(wv.x, hv.y, A0.y);
                A0.z = fmaf(wv.x, hv.z, A0.z); A0.w = fmaf(wv.x, hv.w, A0.w);
                A1.x = fmaf(wv.y, hv.x, A1.x); A1.y = fmaf(wv.y, hv.y, A1.y);
                A1.z = fmaf(wv.y, hv.z, A1.z); A1.w = fmaf(wv.y, hv.w, A1.w);
                A2.x = fmaf(wv.z, hv.x, A2.x); A2.y = fmaf(wv.z, hv.y, A2.y);
                A2.z = fmaf(wv.z, hv.z, A2.z); A2.w = fmaf(wv.z, hv.w, A2.w);
                A3.x = fmaf(wv.w, hv.x, A3.x); A3.y = fmaf(wv.w, hv.y, A3.y);
                A3.z = fmaf(wv.w, hv.z, A3.z); A3.w = fmaf(wv.w, hv.w, A3.w);
            }
        }
        if (L2a) {
            const float4* ph = hp4 + (size_t)(64 + kb2) * 8 + bq2;
            const float4* pw = w24 + (size_t)kb2 * 4 + rq2;
            #pragma unroll 8
            for (int k = 0; k < 24; ++k) {
                const float4 hv = ph[k * 8];
                const float4 wv = pw[k * 4];
                E0.x = fmaf(wv.x, hv.x, E0.x); E0.y = fmaf(wv.x, hv.y, E0.y);
                E0.z = fmaf(wv.x, hv.z, E0.z); E0.w = fmaf(wv.x, hv.w, E0.w);
                E1.x = fmaf(wv.y, hv.x, E1.x); E1.y = fmaf(wv.y, hv.y, E1.y);
                E1.z = fmaf(wv.y, hv.z, E1.z); E1.w = fmaf(wv.y, hv.w, E1.w);
                E2.x = fmaf(wv.z, hv.x, E2.x); E2.y = fmaf(wv.z, hv.y, E2.y);
                E2.z = fmaf(wv.z, hv.z, E2.z); E2.w = fmaf(wv.z, hv.w, E2.w);
                E3.x = fmaf(wv.w, hv.x, E3.x); E3.y = fmaf(wv.w, hv.y, E3.y);
                E3.z = fmaf(wv.w, hv.z, E3.z); E3.w = fmaf(wv.w, hv.w, E3.w);
            }
        }
        __syncthreads();   // sync0: panel fully consumed

        // ---- B1: k-partials into scratch (aliases consumed panel) ----
        if (L1a && kseg != 0) {
            float4* s4 = (float4*)&dyn[((kseg - 1) << 10) + (pos << 4)];
            s4[0 ^ sw1] = A0; s4[1 ^ sw1] = A1; s4[2 ^ sw1] = A2; s4[3 ^ sw1] = A3;
        }
        if (L2a && kseg2 != 15) {
            float4* s4 = (float4*)&dyn[7168 + (kseg2 << 9) + (pos2 << 4)];
            s4[0 ^ sw2] = E0; s4[1 ^ sw2] = E1; s4[2 ^ sw2] = E2; s4[3 ^ sw2] = E3;
        }
        __syncthreads();   // sync1

        // ---- B2: reduce + bias + gating + coherent h stores ----
        if (L1a && kseg == 0) {
            #pragma unroll
            for (int s = 0; s < 7; ++s) {
                const float4* r4 = (const float4*)&dyn[(s << 10) + (pos << 4)];
                const float4 p0 = r4[0 ^ sw1], p1 = r4[1 ^ sw1];
                const float4 p2 = r4[2 ^ sw1], p3 = r4[3 ^ sw1];
                A0.x += p0.x; A0.y += p0.y; A0.z += p0.z; A0.w += p0.w;
                A1.x += p1.x; A1.y += p1.y; A1.z += p1.z; A1.w += p1.w;
                A2.x += p2.x; A2.y += p2.y; A2.z += p2.z; A2.w += p2.w;
                A3.x += p3.x; A3.y += p3.y; A3.z += p3.z; A3.w += p3.w;
            }
            A0.x += b1v.x; A0.y += b1v.x; A0.z += b1v.x; A0.w += b1v.x;
            A1.x += b1v.y; A1.y += b1v.y; A1.z += b1v.y; A1.w += b1v.y;
            A2.x += b1v.z; A2.y += b1v.z; A2.z += b1v.z; A2.w += b1v.z;
            A3.x += b1v.w; A3.y += b1v.w; A3.z += b1v.w; A3.w += b1v.w;
            float hx = gate_h(A0.x, A1.x, A2.x, A3.x, c1r.x);
            float hy = gate_h(A0.y, A1.y, A2.y, A3.y, c1r.y);
            float hz = gate_h(A0.z, A1.z, A2.z, A3.z, c1r.z);
            float hw = gate_h(A0.w, A1.w, A2.w, A3.w, c1r.w);
            const size_t hb = ((size_t)((t & 1) * 8 + grp) * H1u + (j * 8 + rq)) * 16 + bq * 2;
            __hip_atomic_store(&h1qw[hb],     pack2(hx, hy), __ATOMIC_RELAXED, __HIP_MEMORY_SCOPE_AGENT);
            __hip_atomic_store(&h1qw[hb + 1], pack2(hz, hw), __ATOMIC_RELAXED, __HIP_MEMORY_SCOPE_AGENT);
        }
        if (L2a && kseg2 == 15) {
            #pragma unroll
            for (int s = 0; s < 15; ++s) {
                const float4* r4 = (const float4*)&dyn[7168 + (s << 9) + (pos2 << 4)];
                const float4 p0 = r4[0 ^ sw2], p1 = r4[1 ^ sw2];
                const float4 p2 = r4[2 ^ sw2], p3 = r4[3 ^ sw2];
                E0.x += p0.x; E0.y += p0.y; E0.z += p0.z; E0.w += p0.w;
                E1.x += p1.x; E1.y += p1.y; E1.z += p1.z; E1.w += p1.w;
                E2.x += p2.x; E2.y += p2.y; E2.z += p2.z; E2.w += p2.w;
                E3.x += p3.x; E3.y += p3.y; E3.z += p3.z; E3.w += p3.w;
            }
            E0.x += b2v.x; E0.y += b2v.x; E0.z += b2v.x; E0.w += b2v.x;
            E1.x += b2v.y; E1.y += b2v.y; E1.z += b2v.y; E1.w += b2v.y;
            E2.x += b2v.z; E2.y += b2v.z; E2.z += b2v.z; E2.w += b2v.z;
            E3.x += b2v.w; E3.y += b2v.w; E3.z += b2v.w; E3.w += b2v.w;
            float hx = gate_h(E0.x, E1.x, E2.x, E3.x, c2r.x);
            float hy = gate_h(E0.y, E1.y, E2.y, E3.y, c2r.y);
            float hz = gate_h(E0.z, E1.z, E2.z, E3.z, c2r.z);
            float hw = gate_h(E0.w, E1.w, E2.w, E3.w, c2r.w);
            const size_t hb = ((size_t)(((t + 1) & 1) * 8 + grp) * H2u + (j * 4 + rq2)) * 16 + bq2 * 2;
            __hip_atomic_store(&h2qw[hb],     pack2(hx, hy), __ATOMIC_RELAXED, __HIP_MEMORY_SCOPE_AGENT);
            __hip_atomic_store(&h2qw[hb + 1], pack2(hz, hw), __ATOMIC_RELAXED, __HIP_MEMORY_SCOPE_AGENT);
            float4 hv = {hx, hy, hz, hw};
            *(float4*)&h2tile[rq2 * 36 + bq2 * 4] = hv;
        }
        __syncthreads();   // sync2: drains all waves' vmem stores (vmcnt 0 in barrier)

        if (L1a && tid == 0)
            __hip_atomic_fetch_add(ctr, 1u, __ATOMIC_RELEASE, __HIP_MEMORY_SCOPE_AGENT);

        // ---- F: out writes + x prefetch (off the barrier critical path) ----
        if (L2a && tid < 32) {
            const int s = t - 1;
            float4 hv = {h2tile[0 * 36 + tid], h2tile[1 * 36 + tid],
                         h2tile[2 * 36 + tid], h2tile[3 * 36 + tid]};
            *(float4*)&out[((size_t)(b0 + tid) * Tt + s) * H2u + j * 4] = hv;
            if (s == Tt - 1)
                *(float4*)&out[(size_t)Bb * Tt * H2u + (size_t)(b0 + tid) * H2u + j * 4] = hv;
        }
        if (t + 1 < Tt) stage_x(x, dyn, b0, t + 1, tid);

        // ---- barrier + stage next panel ----
        if (L1a) {
            if (tid == 0) {
                const unsigned tgt = 32u * (unsigned)(t + 1);
                while (__hip_atomic_load(ctr, __ATOMIC_RELAXED, __HIP_MEMORY_SCOPE_AGENT) < tgt)
                    __builtin_amdgcn_s_sleep(2);
            }
            __syncthreads();   // sync3
            __builtin_amdgcn_fence(__ATOMIC_ACQUIRE, "workgroup");
            stage_h(h1q, h2q, dyn, (t & 1), ((t + 1) & 1), grp, tid);
            __syncthreads();   // sync4: panel ready for t+1
        }
    }
}

extern "C" void kernel_launch(void* const* d_in, const int* in_sizes, int n_in,
                              void* d_out, int out_size, void* d_ws, size_t ws_size,
                              hipStream_t stream) {
    const float* x    = (const float*)d_in[0];
    const float* Wih1 = (const float*)d_in[1];
    const float* Whh1 = (const float*)d_in[2];
    const float* bih1 = (const float*)d_in[3];
    const float* bhh1 = (const float*)d_in[4];
    const float* Wih2 = (const float*)d_in[5];
    const float* Whh2 = (const float*)d_in[6];
    const float* bih2 = (const float*)d_in[7];
    const float* bhh2 = (const float*)d_in[8];
    float* ws  = (float*)d_ws;
    float* out = (float*)d_out;

    prep3<<<512, 256, 0, stream>>>(Wih1, Whh1, bih1, bhh1,
                                   Wih2, Whh2, bih2, bhh2, ws);
    // zero h parity buffers + barrier counters every launch (deterministic)
    hipMemsetAsync((void*)(ws + OFF_H1G), 0,
                   (size_t)(SZ_H1G + SZ_H2G + SZ_CTR) * sizeof(float), stream);
    lstm_v3<<<NBLK, NTHR, 0, stream>>>(
        x, ws,
        ws + OFF_H1G, ws + OFF_H2G,
        (unsigned*)(ws + OFF_CTR), out);
}